// Round 1
// baseline (347.080 us; speedup 1.0000x reference)
//
#include <hip/hip_runtime.h>
#include <math.h>

// ---------------------------------------------------------------------------
// IPOT on MI355X — round 6.
// Math (exact, verified absmax 0.0 in R1/R2/R4):
//   Cl = -C;  M_t = exp((t+1)*Cl)
//   row:  r_i = sum_j M_t(i,j) s_j ; a = 1/(n r)
//   col:  c_j = sum_i M_t(i,j) a_i ; b = 1/c (2^10 inj); s' = b^2/b_prev/1024
//   final G(A,B) = (1/(256*1024)) sum_k P(k,A) R(k,B)
// R6 (R5's residual = 1 wave/SIMD latency exposure, Occupancy 1.48%):
//   - Same 32 WGs / 32 rows per WG / same NREP=4 atomic+counter protocol,
//     but 1024 threads/WG: thread owns 2 rows x 16 cols -> C[2][16]+E[2][16]
//     = 64 floats, ~100 VGPR live -> launch_bounds(1024,4) = 4 waves/SIMD.
//   - Col reduce: 16 wave-partials in LDS buf[16][1024]; owner = 1 col/thread
//     (16 scalar ds_read_b32, conflict-free), 1 atomicAdd/thread (same count).
//   - E_{t+1} recomputed AFTER the adds (overlaps atomic chain / WG skew).
// ---------------------------------------------------------------------------

#define NWG 32
#define TPB 1024
#define NIT 50
#define NREP 4

typedef unsigned long long ull;

// ws offsets in floats
constexpr int CL_OFF   = 0;                           // -C [1024*1024]
constexpr int CVEC_OFF = 1024 * 1024;                 // [3][NREP][1024]
constexpr int CNT_OFF  = CVEC_OFF + 3 * NREP * 1024;  // 4 group counters (pad 16)
// total ~ 4.05 MB

// ---------------- C = 1 - xhat yhat^T (norms fused) ; Cl = -C ---------------
__global__ __launch_bounds__(256) void k_gemm(const float* __restrict__ X,
                                              const float* __restrict__ Y,
                                              float* __restrict__ ws) {
    __shared__ float As[32][68];
    __shared__ float Bs[32][68];
    __shared__ float nX[64], nY[64];
    float* Cl = ws + CL_OFF;

    int tid = threadIdx.x;
    int tx = tid & 15, ty = tid >> 4;
    int bx = blockIdx.x, by = blockIdx.y;
    int lr0 = tid >> 3;          // 0..31
    int kq  = (tid & 7) * 4;     // 0..28

    float acc[4][4] = {};
    float sx0 = 0.f, sx1 = 0.f, sy0 = 0.f, sy1 = 0.f;
    for (int k0 = 0; k0 < 512; k0 += 32) {
        float4 xa = *(const float4*)(X + (size_t)(by * 64 + lr0) * 512 + k0 + kq);
        float4 xb = *(const float4*)(X + (size_t)(by * 64 + lr0 + 32) * 512 + k0 + kq);
        float4 ya = *(const float4*)(Y + (size_t)(bx * 64 + lr0) * 512 + k0 + kq);
        float4 yb = *(const float4*)(Y + (size_t)(bx * 64 + lr0 + 32) * 512 + k0 + kq);
        sx0 += xa.x * xa.x + xa.y * xa.y + xa.z * xa.z + xa.w * xa.w;
        sx1 += xb.x * xb.x + xb.y * xb.y + xb.z * xb.z + xb.w * xb.w;
        sy0 += ya.x * ya.x + ya.y * ya.y + ya.z * ya.z + ya.w * ya.w;
        sy1 += yb.x * yb.x + yb.y * yb.y + yb.z * yb.z + yb.w * yb.w;
        As[kq + 0][lr0] = xa.x; As[kq + 1][lr0] = xa.y;
        As[kq + 2][lr0] = xa.z; As[kq + 3][lr0] = xa.w;
        As[kq + 0][lr0 + 32] = xb.x; As[kq + 1][lr0 + 32] = xb.y;
        As[kq + 2][lr0 + 32] = xb.z; As[kq + 3][lr0 + 32] = xb.w;
        Bs[kq + 0][lr0] = ya.x; Bs[kq + 1][lr0] = ya.y;
        Bs[kq + 2][lr0] = ya.z; Bs[kq + 3][lr0] = ya.w;
        Bs[kq + 0][lr0 + 32] = yb.x; Bs[kq + 1][lr0 + 32] = yb.y;
        Bs[kq + 2][lr0 + 32] = yb.z; Bs[kq + 3][lr0 + 32] = yb.w;
        __syncthreads();
#pragma unroll
        for (int kk = 0; kk < 32; ++kk) {
            float4 a4 = *(const float4*)&As[kk][4 * ty];
            float4 b4 = *(const float4*)&Bs[kk][4 * tx];
            float av[4] = {a4.x, a4.y, a4.z, a4.w};
            float bv[4] = {b4.x, b4.y, b4.z, b4.w};
#pragma unroll
            for (int r = 0; r < 4; ++r)
#pragma unroll
                for (int q = 0; q < 4; ++q) acc[r][q] += av[r] * bv[q];
        }
        __syncthreads();
    }
#pragma unroll
    for (int m = 1; m < 8; m <<= 1) {
        sx0 += __shfl_xor(sx0, m, 64);
        sx1 += __shfl_xor(sx1, m, 64);
        sy0 += __shfl_xor(sy0, m, 64);
        sy1 += __shfl_xor(sy1, m, 64);
    }
    if ((tid & 7) == 0) {
        nX[lr0] = sx0; nX[lr0 + 32] = sx1;
        nY[lr0] = sy0; nY[lr0 + 32] = sy1;
    }
    __syncthreads();

    int i0 = by * 64 + 4 * ty, j0 = bx * 64 + 4 * tx;
    float vy[4];
#pragma unroll
    for (int q = 0; q < 4; ++q) vy[q] = 1.0f / sqrtf(nY[4 * tx + q]);
#pragma unroll
    for (int r = 0; r < 4; ++r) {
        float vx = 1.0f / sqrtf(nX[4 * ty + r]);
        float4 o;
        o.x = acc[r][0] * vx * vy[0] - 1.0f;  // Cl = dot - 1 = -C
        o.y = acc[r][1] * vx * vy[1] - 1.0f;
        o.z = acc[r][2] * vx * vy[2] - 1.0f;
        o.w = acc[r][3] * vx * vy[3] - 1.0f;
        *(float4*)(Cl + (size_t)(i0 + r) * 1024 + j0) = o;
    }
}

// ---------------------- persistent IPOT iteration --------------------------
__global__ __launch_bounds__(1024, 4) void k_ipot(float* __restrict__ ws,
                                                  float* __restrict__ out) {
    __shared__ float sL[1024];       // s (loop) / b (epilogue)
    __shared__ float aL[32];
    __shared__ float buf[16 * 1024]; // colp[16][1024]; epilogue Ps[0..2047]+Rs[2048..]
    __shared__ float twv[16];

    const int g = blockIdx.x, tid = threadIdx.x;
    const int rs = tid >> 6, lane = tid & 63;  // wave id (0..15) / lane
    float* Cl   = ws + CL_OFF;
    float* cvec = ws + CVEC_OFF;
    unsigned* grp = (unsigned*)(ws + CNT_OFF);

    // thread owns rows g*32 + rs*2 + i (i<2), cols lane*16 + u (u<16)
    float C[2][16], E[2][16];
#pragma unroll
    for (int i = 0; i < 2; ++i) {
        const float* src = Cl + (size_t)(g * 32 + rs * 2 + i) * 1024 + lane * 16;
#pragma unroll
        for (int q = 0; q < 4; ++q) {
            float4 c = *(const float4*)(src + 4 * q);
            C[i][4 * q + 0] = c.x; C[i][4 * q + 1] = c.y;
            C[i][4 * q + 2] = c.z; C[i][4 * q + 3] = c.w;
        }
    }
#pragma unroll
    for (int i = 0; i < 2; ++i)
#pragma unroll
        for (int u = 0; u < 16; ++u) E[i][u] = __expf(C[i][u]);  // round 0

    float bv = 1.0f;  // b_prev for owned col (= tid)

    for (int t = 0; t < NIT; ++t) {
        if (t == 0) {
            sL[tid] = 1.0f / 1024.0f;
        } else {
            if (tid == 0) {  // poll: round t-1 adds complete everywhere
                unsigned tgt = (unsigned)t * 8u;
                long gd = 0;
                while (__hip_atomic_load(&grp[0], __ATOMIC_RELAXED, __HIP_MEMORY_SCOPE_AGENT) < tgt ||
                       __hip_atomic_load(&grp[1], __ATOMIC_RELAXED, __HIP_MEMORY_SCOPE_AGENT) < tgt ||
                       __hip_atomic_load(&grp[2], __ATOMIC_RELAXED, __HIP_MEMORY_SCOPE_AGENT) < tgt ||
                       __hip_atomic_load(&grp[3], __ATOMIC_RELAXED, __HIP_MEMORY_SCOPE_AGENT) < tgt) {
                    __builtin_amdgcn_s_sleep(1);
                    if (++gd > 2000000) break;  // anti-hang bailout
                }
            }
            __syncthreads();
            // readback this thread's col (=tid) from buffer (t-1)%3, 4 replicas
            const float* rb = cvec + ((t + 2) % 3) * (NREP * 1024) + tid;
            float r0 = __hip_atomic_load(rb + 0 * 1024, __ATOMIC_RELAXED, __HIP_MEMORY_SCOPE_AGENT);
            float r1 = __hip_atomic_load(rb + 1 * 1024, __ATOMIC_RELAXED, __HIP_MEMORY_SCOPE_AGENT);
            float r2 = __hip_atomic_load(rb + 2 * 1024, __ATOMIC_RELAXED, __HIP_MEMORY_SCOPE_AGENT);
            float r3 = __hip_atomic_load(rb + 3 * 1024, __ATOMIC_RELAXED, __HIP_MEMORY_SCOPE_AGENT);
            if (t >= 2 && tid < 64) {  // zero buffer (t+1)%3 (read at t-1, all done)
                ull* zb = (ull*)(cvec + ((t + 1) % 3) * (NREP * 1024)) + g * 64 + tid;
                __hip_atomic_store(zb, 0ull, __ATOMIC_RELAXED, __HIP_MEMORY_SCOPE_AGENT);
            }
            float c = r0 + r1 + r2 + r3;
            float b = 1.0f / c;
            sL[tid] = b * b / bv * (1.0f / 1024.0f);  // 2^-10 inj
            bv = b;
        }
        __syncthreads();

        // row phase: rp[i] = sum_u E[i][u] * s[lane*16+u]; wave-local reduce
        float sv[16];
#pragma unroll
        for (int q = 0; q < 4; ++q) {
            float4 s4 = *(const float4*)&sL[lane * 16 + 4 * q];
            sv[4 * q + 0] = s4.x; sv[4 * q + 1] = s4.y;
            sv[4 * q + 2] = s4.z; sv[4 * q + 3] = s4.w;
        }
        float rp[2];
#pragma unroll
        for (int i = 0; i < 2; ++i) {
            float a = 0.0f;
#pragma unroll
            for (int u = 0; u < 16; ++u) a += E[i][u] * sv[u];
            rp[i] = a;
        }
#pragma unroll
        for (int m = 1; m < 64; m <<= 1) {
            rp[0] += __shfl_xor(rp[0], m, 64);
            rp[1] += __shfl_xor(rp[1], m, 64);
        }
        if (lane == 0) {
            aL[rs * 2 + 0] = 1.0f / (1024.0f * rp[0]);
            aL[rs * 2 + 1] = 1.0f / (1024.0f * rp[1]);
        }
        __syncthreads();

        // col phase: partials over this wave's 2 rows for its 16 cols
        float av0 = aL[rs * 2 + 0], av1 = aL[rs * 2 + 1];
#pragma unroll
        for (int q = 0; q < 4; ++q) {
            float4 o;
            o.x = E[0][4*q+0] * av0 + E[1][4*q+0] * av1;
            o.y = E[0][4*q+1] * av0 + E[1][4*q+1] * av1;
            o.z = E[0][4*q+2] * av0 + E[1][4*q+2] * av1;
            o.w = E[0][4*q+3] * av0 + E[1][4*q+3] * av1;
            *(float4*)&buf[rs * 1024 + lane * 16 + 4 * q] = o;
        }
        __syncthreads();

        // owner (1 col/thread): sum 16 wave-partials, atomicAdd to replica g&3
        float csum = 0.0f;
#pragma unroll
        for (int w = 0; w < 16; ++w) csum += buf[w * 1024 + tid];
        float* wb = cvec + (t % 3) * (NREP * 1024) + (g & 3) * 1024 + tid;
        atomicAdd(wb, csum);
        __syncthreads();  // per-thread vmcnt(0) drain: all adds at LLC
        if (tid == 0)
            __hip_atomic_fetch_add(&grp[g >> 3], 1u, __ATOMIC_RELAXED,
                                   __HIP_MEMORY_SCOPE_AGENT);

        // recompute E for next round (overlaps atomic chain / WG skew)
        if (t < NIT - 1) {
            const float kf = (float)(t + 2);
#pragma unroll
            for (int i = 0; i < 2; ++i)
#pragma unroll
                for (int u = 0; u < 16; ++u) E[i][u] = __expf(kf * C[i][u]);
        }
    }

    // ------------- epilogue: E = exp(50*Cl), aL = round-49 a ----------------
    if (tid == 0) {
        unsigned tgt = (unsigned)NIT * 8u;
        long gd = 0;
        while (__hip_atomic_load(&grp[0], __ATOMIC_RELAXED, __HIP_MEMORY_SCOPE_AGENT) < tgt ||
               __hip_atomic_load(&grp[1], __ATOMIC_RELAXED, __HIP_MEMORY_SCOPE_AGENT) < tgt ||
               __hip_atomic_load(&grp[2], __ATOMIC_RELAXED, __HIP_MEMORY_SCOPE_AGENT) < tgt ||
               __hip_atomic_load(&grp[3], __ATOMIC_RELAXED, __HIP_MEMORY_SCOPE_AGENT) < tgt) {
            __builtin_amdgcn_s_sleep(1);
            if (++gd > 2000000) break;
        }
    }
    __syncthreads();
    {   // final b for this thread's col -> sL (as bArr)
        const float* rb = cvec + ((NIT - 1) % 3) * (NREP * 1024) + tid;
        float r0 = __hip_atomic_load(rb + 0 * 1024, __ATOMIC_RELAXED, __HIP_MEMORY_SCOPE_AGENT);
        float r1 = __hip_atomic_load(rb + 1 * 1024, __ATOMIC_RELAXED, __HIP_MEMORY_SCOPE_AGENT);
        float r2 = __hip_atomic_load(rb + 2 * 1024, __ATOMIC_RELAXED, __HIP_MEMORY_SCOPE_AGENT);
        float r3 = __hip_atomic_load(rb + 3 * 1024, __ATOMIC_RELAXED, __HIP_MEMORY_SCOPE_AGENT);
        sL[tid] = 1.0f / (r0 + r1 + r2 + r3);
    }
    __syncthreads();

    // P(k,A=lane) and R(k,B=lane) for this thread's 2 rows (A-block == lane)
    float* Ps = buf;          // [32][64]
    float* Rs = buf + 2048;   // [32][64]
    float bl[16];
#pragma unroll
    for (int q = 0; q < 4; ++q) {
        float4 b4 = *(const float4*)&sL[lane * 16 + 4 * q];
        bl[4 * q + 0] = b4.x; bl[4 * q + 1] = b4.y;
        bl[4 * q + 2] = b4.z; bl[4 * q + 3] = b4.w;
    }
#pragma unroll
    for (int i = 0; i < 2; ++i) {
        float p = 0.0f, r = 0.0f;
#pragma unroll
        for (int u = 0; u < 16; ++u) {
            p += C[i][u];
            r += E[i][u] * bl[u];
        }
        Ps[(rs * 2 + i) * 64 + lane] = -p;              // C = -Cl
        Rs[(rs * 2 + i) * 64 + lane] = aL[rs * 2 + i] * r;
    }
    __syncthreads();

    // G partial (this WG's 32 k-rows) -> atomicAdd into zeroed d_out
    float Rk[32];
#pragma unroll
    for (int k = 0; k < 32; ++k) Rk[k] = Rs[k * 64 + lane];  // B = lane
    const float sc = 1.0f / (256.0f * 1024.0f);
    float tsum = 0.0f;
#pragma unroll
    for (int q = 0; q < 4; ++q) {
        int o = tid + 1024 * q;
        int A = o >> 6;  // = rs + 16*q
        float acc = 0.0f;
#pragma unroll
        for (int k = 0; k < 32; ++k) acc += Ps[k * 64 + A] * Rk[k];
        float val = acc * sc;
        atomicAdd(out + o, val);
        if (A == lane) tsum += val;
    }
#pragma unroll
    for (int m = 1; m < 64; m <<= 1) tsum += __shfl_xor(tsum, m, 64);
    if (lane == 0) twv[rs] = tsum;
    __syncthreads();
    if (tid == 0) {
        float ts = 0.0f;
#pragma unroll
        for (int w = 0; w < 16; ++w) ts += twv[w];
        atomicAdd(out + 4096, ts);
    }
}

// ---------------------------------------------------------------------------
extern "C" void kernel_launch(void* const* d_in, const int* in_sizes, int n_in,
                              void* d_out, int out_size, void* d_ws, size_t ws_size,
                              hipStream_t stream) {
    const float* X = (const float*)d_in[0];  // t_prob [1024,512]
    const float* Y = (const float*)d_in[1];  // v_prob [1024,512]
    float* out = (float*)d_out;              // [64*64 + 1]
    float* ws  = (float*)d_ws;

    // zero cvec + counters (ws poisoned each call), zero d_out
    (void)hipMemsetAsync((char*)d_ws + (size_t)CVEC_OFF * 4, 0,
                         (3 * NREP * 1024 + 16) * 4, stream);
    (void)hipMemsetAsync(d_out, 0, (size_t)out_size * 4, stream);

    k_gemm<<<dim3(16, 16), 256, 0, stream>>>(X, Y, ws);
    k_ipot<<<NWG, TPB, 0, stream>>>(ws, out);
}